// Round 1
// baseline (18765.318 us; speedup 1.0000x reference)
//
#include <hip/hip_runtime.h>
#include <math.h>

// ---------------------------------------------------------------------------
// PointsToImage: ball-query (K=32, R=0.1) -> PointNetConv msg=[x_j, pos_j-pos_dst]
// -> Linear(66,128) -> masked-BatchNorm -> ReLU -> Linear(128,64) -> scatter-max
// into pixel nodes, output [B=32, F=64, 32, 32] fp32.
//
// Pipeline: k_init -> k_ballquery -> k_stats -> k_finalize -> k_self -> k_nbr
// Only VALID messages are ever computed (masked ones can't affect stats or max).
// ---------------------------------------------------------------------------

#define NPTS   32768
#define PB     1024
#define KNB    32
#define BN_EPS 1e-5f

// workspace layout (bytes)
#define WS_NBRS     0            // int[NPTS*KNB]   = 4194304
#define WS_NBRCNT   4194304      // int[NPTS]       = 131072
#define WS_PART     4325376      // float[64*256]   = 65536
#define WS_CNTREP   4390912      // int[64]         = 256
#define WS_SCSH     4391168      // float[256]

__device__ __forceinline__ void atomic_max_float(float* addr, float v) {
    // init value (from k_self) is an arbitrary finite float; this 2-atomic trick
    // is correct for all sign combinations.
    if (v >= 0.0f) atomicMax((int*)addr, __float_as_int(v));
    else           atomicMin((unsigned int*)addr, __float_as_uint(v));
}

__global__ void k_init(float* partials, int* cntrep) {
    int t = blockIdx.x * 256 + threadIdx.x;
    if (t < 64 * 256) partials[t] = 0.0f;
    if (t < 64) cntrep[t] = 0;
}

// --------------------------- ball query ------------------------------------
// one 64-thread block per query point. Exact K-smallest-within-radius with
// (d2, idx) tie-break to match jax.lax.top_k determinism. Arithmetic matches
// the reference bit-exactly: unfused fp32 mul/add, trunc-cast pix.
__global__ void k_ballquery(const float* __restrict__ pos,
                            int* __restrict__ nbrs, int* __restrict__ nbr_cnt) {
    int q = blockIdx.x;
    int lane = threadIdx.x;
    int base = (q >> 10) << 10;
    float qx = pos[2 * q], qy = pos[2 * q + 1];
    int row = min(max((int)(qy * 32.0f), 0), 31);
    int col = min(max((int)(qx * 32.0f), 0), 31);
    int pixq = base + row * 32 + col;

    __shared__ float cd2[256];
    __shared__ int   cidx[256];
    __shared__ int   cnt, ocnt;
    if (lane == 0) { cnt = 0; ocnt = 0; }
    __syncthreads();

    for (int j = lane; j < PB; j += 64) {
        int g = base + j;
        float dx = pos[2 * g]     - qx;
        float dy = pos[2 * g + 1] - qy;
        float d2 = __fadd_rn(__fmul_rn(dx, dx), __fmul_rn(dy, dy)); // no FMA contraction
        if (d2 <= 0.01f) {
            int s = atomicAdd(&cnt, 1);
            if (s < 256) { cd2[s] = d2; cidx[s] = g; }
        }
    }
    __syncthreads();
    int c = min(cnt, 256);
    for (int i = lane; i < c; i += 64) {
        float d2i = cd2[i]; int gi = cidx[i];
        int rank = 0;
        for (int t = 0; t < c; ++t) {
            float d2t = cd2[t]; int gt = cidx[t];
            rank += (d2t < d2i || (d2t == d2i && gt < gi)) ? 1 : 0;
        }
        if (rank < KNB && gi != pixq) {          // top-K, then remove_self_loops
            int s = atomicAdd(&ocnt, 1);
            nbrs[q * KNB + s] = gi;
        }
    }
    __syncthreads();
    if (lane == 0) nbr_cnt[q] = ocnt;
}

// --------------------------- stats pass ------------------------------------
// wave-per-query, 8-message groups. lane owns features f and f+64.
// Accumulates sum(z), sum(z^2) over all valid messages (incl. self loops).
__launch_bounds__(256)
__global__ void k_stats(const float* __restrict__ x, const float* __restrict__ pos,
                        const float* __restrict__ W1, const float* __restrict__ b1,
                        const int* __restrict__ nbrs, const int* __restrict__ nbr_cnt,
                        float* __restrict__ partials, int* __restrict__ cntrep) {
    __shared__ float w1[66 * 128];
    __shared__ float stage[4][8][64];
    __shared__ float lsum[256];
    __shared__ int lcnt;
    int tid = threadIdx.x;
    for (int i = tid; i < 66 * 128; i += 256) w1[i] = W1[i];
    lsum[tid] = 0.0f;
    if (tid == 0) lcnt = 0;
    __syncthreads();

    int wave = tid >> 6, lane = tid & 63;
    int q = blockIdx.x * 4 + wave;
    int f0 = lane, f1 = lane + 64;
    int b = q >> 10;
    float qx = pos[2 * q], qy = pos[2 * q + 1];
    int row = min(max((int)(qy * 32.0f), 0), 31);
    int col = min(max((int)(qx * 32.0f), 0), 31);
    int pixq = (b << 10) + row * 32 + col;
    float tx = pos[2 * pixq], ty = pos[2 * pixq + 1];
    int m = nbr_cnt[q];
    int tot = m + 1;                    // + self message
    float b10 = b1[f0], b11 = b1[f1];
    float w64f0 = w1[64 * 128 + f0], w65f0 = w1[65 * 128 + f0];
    float w64f1 = w1[64 * 128 + f1], w65f1 = w1[65 * 128 + f1];
    float s0 = 0, s1 = 0, ss0 = 0, ss1 = 0;
    const float4* stage4 = (const float4*)&stage[wave][0][0];

    for (int basei = 0; basei < tot; basei += 8) {
        int g = min(8, tot - basei);
        float rx[8], ry[8];
#pragma unroll
        for (int mm = 0; mm < 8; ++mm) { rx[mm] = 0.0f; ry[mm] = 0.0f; }
        __builtin_amdgcn_wave_barrier();
#pragma unroll
        for (int mm = 0; mm < 8; ++mm) {
            if (mm < g) {
                int gi = basei + mm;
                int src = (gi == 0) ? q : nbrs[q * KNB + gi - 1];
                if (gi != 0) {
                    rx[mm] = pos[2 * src] - tx;
                    ry[mm] = pos[2 * src + 1] - ty;
                }
                stage[wave][mm][lane] = x[src * 64 + lane];
            }
        }
        __builtin_amdgcn_wave_barrier();
        float z0[8], z1[8];
#pragma unroll
        for (int mm = 0; mm < 8; ++mm) { z0[mm] = b10; z1[mm] = b11; }
#pragma unroll
        for (int k4 = 0; k4 < 16; ++k4) {
            float wa0 = w1[(k4 * 4 + 0) * 128 + f0], wa1 = w1[(k4 * 4 + 1) * 128 + f0];
            float wa2 = w1[(k4 * 4 + 2) * 128 + f0], wa3 = w1[(k4 * 4 + 3) * 128 + f0];
            float wb0 = w1[(k4 * 4 + 0) * 128 + f1], wb1 = w1[(k4 * 4 + 1) * 128 + f1];
            float wb2 = w1[(k4 * 4 + 2) * 128 + f1], wb3 = w1[(k4 * 4 + 3) * 128 + f1];
#pragma unroll
            for (int mm = 0; mm < 8; ++mm) {
                float4 mk = stage4[mm * 16 + k4];
                z0[mm] += mk.x * wa0 + mk.y * wa1 + mk.z * wa2 + mk.w * wa3;
                z1[mm] += mk.x * wb0 + mk.y * wb1 + mk.z * wb2 + mk.w * wb3;
            }
        }
#pragma unroll
        for (int mm = 0; mm < 8; ++mm) {
            if (mm < g) {
                float zz0 = z0[mm] + rx[mm] * w64f0 + ry[mm] * w65f0;
                float zz1 = z1[mm] + rx[mm] * w64f1 + ry[mm] * w65f1;
                s0 += zz0; ss0 += zz0 * zz0;
                s1 += zz1; ss1 += zz1 * zz1;
            }
        }
    }
    atomicAdd(&lsum[f0], s0);
    atomicAdd(&lsum[f1], s1);
    atomicAdd(&lsum[128 + f0], ss0);
    atomicAdd(&lsum[128 + f1], ss1);
    if (lane == 0) atomicAdd(&lcnt, tot);
    __syncthreads();
    int rep = blockIdx.x & 63;
    atomicAdd(&partials[rep * 256 + tid], lsum[tid]);
    if (tid == 0) atomicAdd(&cntrep[rep], lcnt);
}

__global__ void k_finalize(const float* __restrict__ gamma, const float* __restrict__ beta,
                           const float* __restrict__ partials, const int* __restrict__ cntrep,
                           float* __restrict__ scsh) {
    int f = threadIdx.x;   // 128 threads
    float s = 0, ss = 0, cnt = 0;
    for (int r = 0; r < 64; ++r) {
        s  += partials[r * 256 + f];
        ss += partials[r * 256 + 128 + f];
        cnt += (float)cntrep[r];
    }
    float mean = s / cnt;
    float var = ss / cnt - mean * mean;
    float sc = gamma[f] / sqrtf(var + BN_EPS);
    scsh[f] = sc;
    scsh[128 + f] = beta[f] - mean * sc;
}

// --------------------------- self-loop pass --------------------------------
// msg=[x_i,0,0] -> MLP -> plain store (each output element written exactly once;
// doubles as initialization of d_out). wave handles 8 nodes.
__launch_bounds__(256, 2)
__global__ void k_self(const float* __restrict__ x, const float* __restrict__ W1,
                       const float* __restrict__ b1, const float* __restrict__ W2,
                       const float* __restrict__ b2, const float* __restrict__ scsh,
                       float* __restrict__ out) {
    __shared__ float w1[64 * 128];     // relpos rows unused (rel = 0)
    __shared__ float stage[4][8][64];
    __shared__ float hbuf[4][8][128];
    int tid = threadIdx.x;
    for (int i = tid; i < 64 * 128; i += 256) w1[i] = W1[i];
    __syncthreads();
    int wave = tid >> 6, lane = tid & 63;
    int f0 = lane, f1 = lane + 64;
    float b10 = b1[f0], b11 = b1[f1];
    float sc0 = scsh[f0], sh0 = scsh[128 + f0];
    float sc1 = scsh[f1], sh1 = scsh[128 + f1];
    float bo = b2[lane];
    float w2c[128];
#pragma unroll
    for (int f = 0; f < 128; ++f) w2c[f] = W2[f * 64 + lane];

    int nbase = (blockIdx.x * 4 + wave) * 8;
#pragma unroll
    for (int mm = 0; mm < 8; ++mm)
        stage[wave][mm][lane] = x[(nbase + mm) * 64 + lane];
    __builtin_amdgcn_wave_barrier();

    const float4* stage4 = (const float4*)&stage[wave][0][0];
    float z0[8], z1[8];
#pragma unroll
    for (int mm = 0; mm < 8; ++mm) { z0[mm] = b10; z1[mm] = b11; }
#pragma unroll
    for (int k4 = 0; k4 < 16; ++k4) {
        float wa0 = w1[(k4 * 4 + 0) * 128 + f0], wa1 = w1[(k4 * 4 + 1) * 128 + f0];
        float wa2 = w1[(k4 * 4 + 2) * 128 + f0], wa3 = w1[(k4 * 4 + 3) * 128 + f0];
        float wb0 = w1[(k4 * 4 + 0) * 128 + f1], wb1 = w1[(k4 * 4 + 1) * 128 + f1];
        float wb2 = w1[(k4 * 4 + 2) * 128 + f1], wb3 = w1[(k4 * 4 + 3) * 128 + f1];
#pragma unroll
        for (int mm = 0; mm < 8; ++mm) {
            float4 mk = stage4[mm * 16 + k4];
            z0[mm] += mk.x * wa0 + mk.y * wa1 + mk.z * wa2 + mk.w * wa3;
            z1[mm] += mk.x * wb0 + mk.y * wb1 + mk.z * wb2 + mk.w * wb3;
        }
    }
#pragma unroll
    for (int mm = 0; mm < 8; ++mm) {
        hbuf[wave][mm][f0] = fmaxf(z0[mm] * sc0 + sh0, 0.0f);
        hbuf[wave][mm][f1] = fmaxf(z1[mm] * sc1 + sh1, 0.0f);
    }
    __builtin_amdgcn_wave_barrier();
    const float4* h4 = (const float4*)&hbuf[wave][0][0];
#pragma unroll
    for (int mm = 0; mm < 8; ++mm) {
        float o = bo;
#pragma unroll
        for (int f4 = 0; f4 < 32; ++f4) {
            float4 hh = h4[mm * 32 + f4];
            o += hh.x * w2c[f4 * 4 + 0] + hh.y * w2c[f4 * 4 + 1]
               + hh.z * w2c[f4 * 4 + 2] + hh.w * w2c[f4 * 4 + 3];
        }
        int n = nbase + mm;
        out[(n >> 10) * 65536 + lane * 1024 + (n & 1023)] = o;
    }
}

// --------------------------- neighbor pass ---------------------------------
// wave-per-query; all K messages share target pix(q): max in registers, then
// one atomic per (query, feature). Runs after k_self initialized d_out.
__launch_bounds__(256, 2)
__global__ void k_nbr(const float* __restrict__ x, const float* __restrict__ pos,
                      const float* __restrict__ W1, const float* __restrict__ b1,
                      const float* __restrict__ W2, const float* __restrict__ b2,
                      const float* __restrict__ scsh, const int* __restrict__ nbrs,
                      const int* __restrict__ nbr_cnt, float* __restrict__ out) {
    __shared__ float w1[66 * 128];
    __shared__ float stage[4][8][64];
    __shared__ float hbuf[4][8][128];
    int tid = threadIdx.x;
    for (int i = tid; i < 66 * 128; i += 256) w1[i] = W1[i];
    __syncthreads();
    int wave = tid >> 6, lane = tid & 63;
    int q = blockIdx.x * 4 + wave;
    int f0 = lane, f1 = lane + 64;
    int b = q >> 10;
    float qx = pos[2 * q], qy = pos[2 * q + 1];
    int row = min(max((int)(qy * 32.0f), 0), 31);
    int col = min(max((int)(qx * 32.0f), 0), 31);
    int pixq = (b << 10) + row * 32 + col;
    float tx = pos[2 * pixq], ty = pos[2 * pixq + 1];
    int m = nbr_cnt[q];
    float b10 = b1[f0], b11 = b1[f1];
    float w64f0 = w1[64 * 128 + f0], w65f0 = w1[65 * 128 + f0];
    float w64f1 = w1[64 * 128 + f1], w65f1 = w1[65 * 128 + f1];
    float sc0 = scsh[f0], sh0 = scsh[128 + f0];
    float sc1 = scsh[f1], sh1 = scsh[128 + f1];
    float bo = b2[lane];
    float w2c[128];
#pragma unroll
    for (int f = 0; f < 128; ++f) w2c[f] = W2[f * 64 + lane];
    float omax = -__builtin_inff();
    const float4* stage4 = (const float4*)&stage[wave][0][0];
    const float4* h4 = (const float4*)&hbuf[wave][0][0];

    for (int basei = 0; basei < m; basei += 8) {
        int g = min(8, m - basei);
        float rx[8], ry[8];
#pragma unroll
        for (int mm = 0; mm < 8; ++mm) { rx[mm] = 0.0f; ry[mm] = 0.0f; }
        __builtin_amdgcn_wave_barrier();
#pragma unroll
        for (int mm = 0; mm < 8; ++mm) {
            if (mm < g) {
                int src = nbrs[q * KNB + basei + mm];
                rx[mm] = pos[2 * src] - tx;
                ry[mm] = pos[2 * src + 1] - ty;
                stage[wave][mm][lane] = x[src * 64 + lane];
            }
        }
        __builtin_amdgcn_wave_barrier();
        float z0[8], z1[8];
#pragma unroll
        for (int mm = 0; mm < 8; ++mm) { z0[mm] = b10; z1[mm] = b11; }
#pragma unroll
        for (int k4 = 0; k4 < 16; ++k4) {
            float wa0 = w1[(k4 * 4 + 0) * 128 + f0], wa1 = w1[(k4 * 4 + 1) * 128 + f0];
            float wa2 = w1[(k4 * 4 + 2) * 128 + f0], wa3 = w1[(k4 * 4 + 3) * 128 + f0];
            float wb0 = w1[(k4 * 4 + 0) * 128 + f1], wb1 = w1[(k4 * 4 + 1) * 128 + f1];
            float wb2 = w1[(k4 * 4 + 2) * 128 + f1], wb3 = w1[(k4 * 4 + 3) * 128 + f1];
#pragma unroll
            for (int mm = 0; mm < 8; ++mm) {
                float4 mk = stage4[mm * 16 + k4];
                z0[mm] += mk.x * wa0 + mk.y * wa1 + mk.z * wa2 + mk.w * wa3;
                z1[mm] += mk.x * wb0 + mk.y * wb1 + mk.z * wb2 + mk.w * wb3;
            }
        }
#pragma unroll
        for (int mm = 0; mm < 8; ++mm) {
            if (mm < g) {
                float zz0 = z0[mm] + rx[mm] * w64f0 + ry[mm] * w65f0;
                float zz1 = z1[mm] + rx[mm] * w64f1 + ry[mm] * w65f1;
                hbuf[wave][mm][f0] = fmaxf(zz0 * sc0 + sh0, 0.0f);
                hbuf[wave][mm][f1] = fmaxf(zz1 * sc1 + sh1, 0.0f);
            }
        }
        __builtin_amdgcn_wave_barrier();
#pragma unroll
        for (int mm = 0; mm < 8; ++mm) {
            if (mm < g) {
                float o = bo;
#pragma unroll
                for (int f4 = 0; f4 < 32; ++f4) {
                    float4 hh = h4[mm * 32 + f4];
                    o += hh.x * w2c[f4 * 4 + 0] + hh.y * w2c[f4 * 4 + 1]
                       + hh.z * w2c[f4 * 4 + 2] + hh.w * w2c[f4 * 4 + 3];
                }
                omax = fmaxf(omax, o);
            }
        }
        __builtin_amdgcn_wave_barrier();
    }
    if (m > 0) {
        atomic_max_float(&out[(pixq >> 10) * 65536 + lane * 1024 + (pixq & 1023)], omax);
    }
}

extern "C" void kernel_launch(void* const* d_in, const int* in_sizes, int n_in,
                              void* d_out, int out_size, void* d_ws, size_t ws_size,
                              hipStream_t stream) {
    const float* x     = (const float*)d_in[0];
    const float* pos   = (const float*)d_in[1];
    // d_in[2] = batch (unused: points are sorted, b = idx >> 10)
    const float* W1    = (const float*)d_in[3];
    const float* b1    = (const float*)d_in[4];
    const float* gamma = (const float*)d_in[5];
    const float* beta  = (const float*)d_in[6];
    const float* W2    = (const float*)d_in[7];
    const float* b2    = (const float*)d_in[8];
    float* out = (float*)d_out;
    char* ws = (char*)d_ws;
    int*   nbrs     = (int*)(ws + WS_NBRS);
    int*   nbr_cnt  = (int*)(ws + WS_NBRCNT);
    float* partials = (float*)(ws + WS_PART);
    int*   cntrep   = (int*)(ws + WS_CNTREP);
    float* scsh     = (float*)(ws + WS_SCSH);

    k_init<<<64, 256, 0, stream>>>(partials, cntrep);
    k_ballquery<<<NPTS, 64, 0, stream>>>(pos, nbrs, nbr_cnt);
    k_stats<<<NPTS / 4, 256, 0, stream>>>(x, pos, W1, b1, nbrs, nbr_cnt, partials, cntrep);
    k_finalize<<<1, 128, 0, stream>>>(gamma, beta, partials, cntrep, scsh);
    k_self<<<NPTS / 32, 256, 0, stream>>>(x, W1, b1, W2, b2, scsh, out);
    k_nbr<<<NPTS / 4, 256, 0, stream>>>(x, pos, W1, b1, W2, b2, scsh, nbrs, nbr_cnt, out);
}

// Round 2
// 1436.631 us; speedup vs baseline: 13.0620x; 13.0620x over previous
//
#include <hip/hip_runtime.h>
#include <math.h>

// ---------------------------------------------------------------------------
// PointsToImage: ball-query (K=32, R=0.1) -> PointNetConv msg=[x_j, pos_j-pos_dst]
// -> Linear(66,128) -> masked-BatchNorm -> ReLU -> Linear(128,64) -> scatter-max
// into pixel nodes, output [B=32, F=64, 32, 32] fp32.
//
// Pipeline: k_init -> k_ballquery -> k_stats -> k_finalize -> k_self -> k_nbr
// Only VALID messages are ever computed (masked ones can't affect stats or max).
//
// R2 change: NO per-lane arrays that can demote to scratch (R1 spilled 38 GB).
// W2 lives in LDS; stage/h buffers are unioned (72 KB LDS -> 2 blocks/CU).
// ---------------------------------------------------------------------------

#define NPTS   32768
#define PB     1024
#define KNB    32
#define BN_EPS 1e-5f

// workspace layout (bytes)
#define WS_NBRS     0            // int[NPTS*KNB]   = 4194304
#define WS_NBRCNT   4194304      // int[NPTS]       = 131072
#define WS_PART     4325376      // float[64*256]   = 65536
#define WS_CNTREP   4390912      // int[64]         = 256
#define WS_SCSH     4391168      // float[256]

__device__ __forceinline__ void atomic_max_float(float* addr, float v) {
    // init value (from k_self) is an arbitrary finite float; this 2-atomic trick
    // is correct for all sign combinations.
    if (v >= 0.0f) atomicMax((int*)addr, __float_as_int(v));
    else           atomicMin((unsigned int*)addr, __float_as_uint(v));
}

__global__ void k_init(float* partials, int* cntrep) {
    int t = blockIdx.x * 256 + threadIdx.x;
    if (t < 64 * 256) partials[t] = 0.0f;
    if (t < 64) cntrep[t] = 0;
}

// --------------------------- ball query ------------------------------------
// one 64-thread block per query point. Exact K-smallest-within-radius with
// (d2, idx) tie-break to match jax.lax.top_k determinism. Arithmetic matches
// the reference bit-exactly: unfused fp32 mul/add, trunc-cast pix.
// NOTE: self-loop removal is (src != pix(q)), NOT (src != q) — the reference's
// dst is the pixel-mapped index.
__global__ void k_ballquery(const float* __restrict__ pos,
                            int* __restrict__ nbrs, int* __restrict__ nbr_cnt) {
    int q = blockIdx.x;
    int lane = threadIdx.x;
    int base = (q >> 10) << 10;
    float qx = pos[2 * q], qy = pos[2 * q + 1];
    int row = min(max((int)(qy * 32.0f), 0), 31);
    int col = min(max((int)(qx * 32.0f), 0), 31);
    int pixq = base + row * 32 + col;

    __shared__ float cd2[256];
    __shared__ int   cidx[256];
    __shared__ int   cnt, ocnt;
    if (lane == 0) { cnt = 0; ocnt = 0; }
    __syncthreads();

    for (int j = lane; j < PB; j += 64) {
        int g = base + j;
        float dx = pos[2 * g]     - qx;
        float dy = pos[2 * g + 1] - qy;
        float d2 = __fadd_rn(__fmul_rn(dx, dx), __fmul_rn(dy, dy)); // no FMA contraction
        if (d2 <= 0.01f) {
            int s = atomicAdd(&cnt, 1);
            if (s < 256) { cd2[s] = d2; cidx[s] = g; }
        }
    }
    __syncthreads();
    int c = min(cnt, 256);
    for (int i = lane; i < c; i += 64) {
        float d2i = cd2[i]; int gi = cidx[i];
        int rank = 0;
        for (int t = 0; t < c; ++t) {
            float d2t = cd2[t]; int gt = cidx[t];
            rank += (d2t < d2i || (d2t == d2i && gt < gi)) ? 1 : 0;
        }
        if (rank < KNB && gi != pixq) {          // top-K, then remove_self_loops
            int s = atomicAdd(&ocnt, 1);
            nbrs[q * KNB + s] = gi;
        }
    }
    __syncthreads();
    if (lane == 0) nbr_cnt[q] = ocnt;
}

// --------------------------- stats pass ------------------------------------
// wave-per-query, 8-message groups. lane owns features f=lane and f+64.
// Accumulates sum(z), sum(z^2) over all valid messages (incl. self loops).
__launch_bounds__(256, 2)
__global__ void k_stats(const float* __restrict__ x, const float* __restrict__ pos,
                        const float* __restrict__ W1, const float* __restrict__ b1,
                        const int* __restrict__ nbrs, const int* __restrict__ nbr_cnt,
                        float* __restrict__ partials, int* __restrict__ cntrep) {
    __shared__ float w1s[64 * 128];          // rows 0..63 only (x_j part)
    __shared__ float stage[4][8 * 64];
    __shared__ float lsum[256];
    __shared__ int lcnt;
    int tid = threadIdx.x;
    for (int i = tid; i < 64 * 128; i += 256) w1s[i] = W1[i];
    lsum[tid] = 0.0f;
    if (tid == 0) lcnt = 0;
    __syncthreads();

    int wave = tid >> 6, lane = tid & 63;
    int q = blockIdx.x * 4 + wave;
    int f0 = lane, f1 = lane + 64;
    int b = q >> 10;
    float qx = pos[2 * q], qy = pos[2 * q + 1];
    int row = min(max((int)(qy * 32.0f), 0), 31);
    int col = min(max((int)(qx * 32.0f), 0), 31);
    int pixq = (b << 10) + row * 32 + col;
    float tx = pos[2 * pixq], ty = pos[2 * pixq + 1];
    int m = nbr_cnt[q];
    int tot = m + 1;                    // + self message
    float b10 = b1[f0], b11 = b1[f1];
    float w64f0 = W1[64 * 128 + f0], w65f0 = W1[65 * 128 + f0];  // relpos rows from global
    float w64f1 = W1[64 * 128 + f1], w65f1 = W1[65 * 128 + f1];
    float s0 = 0, s1 = 0, ss0 = 0, ss1 = 0;
    float* st = &stage[wave][0];

    for (int basei = 0; basei < tot; basei += 8) {
        int g = min(8, tot - basei);
        float rx[8], ry[8];
#pragma unroll
        for (int mm = 0; mm < 8; ++mm) { rx[mm] = 0.0f; ry[mm] = 0.0f; }
        __builtin_amdgcn_wave_barrier();
#pragma unroll
        for (int mm = 0; mm < 8; ++mm) {
            if (mm < g) {
                int gi = basei + mm;
                int src = (gi == 0) ? q : nbrs[q * KNB + gi - 1];
                if (gi != 0) {
                    rx[mm] = pos[2 * src] - tx;
                    ry[mm] = pos[2 * src + 1] - ty;
                }
                st[mm * 64 + lane] = x[src * 64 + lane];
            }
        }
        __builtin_amdgcn_wave_barrier();
        float z0[8], z1[8];
#pragma unroll
        for (int mm = 0; mm < 8; ++mm) { z0[mm] = b10; z1[mm] = b11; }
        for (int k4 = 0; k4 < 16; ++k4) {
            float wa0 = w1s[(k4 * 4 + 0) * 128 + f0], wa1 = w1s[(k4 * 4 + 1) * 128 + f0];
            float wa2 = w1s[(k4 * 4 + 2) * 128 + f0], wa3 = w1s[(k4 * 4 + 3) * 128 + f0];
            float wb0 = w1s[(k4 * 4 + 0) * 128 + f1], wb1 = w1s[(k4 * 4 + 1) * 128 + f1];
            float wb2 = w1s[(k4 * 4 + 2) * 128 + f1], wb3 = w1s[(k4 * 4 + 3) * 128 + f1];
#pragma unroll
            for (int mm = 0; mm < 8; ++mm) {
                float4 mk = *(const float4*)&st[mm * 64 + k4 * 4];
                z0[mm] += mk.x * wa0 + mk.y * wa1 + mk.z * wa2 + mk.w * wa3;
                z1[mm] += mk.x * wb0 + mk.y * wb1 + mk.z * wb2 + mk.w * wb3;
            }
        }
#pragma unroll
        for (int mm = 0; mm < 8; ++mm) {
            if (mm < g) {
                float zz0 = z0[mm] + rx[mm] * w64f0 + ry[mm] * w65f0;
                float zz1 = z1[mm] + rx[mm] * w64f1 + ry[mm] * w65f1;
                s0 += zz0; ss0 += zz0 * zz0;
                s1 += zz1; ss1 += zz1 * zz1;
            }
        }
        __builtin_amdgcn_wave_barrier();
    }
    atomicAdd(&lsum[f0], s0);
    atomicAdd(&lsum[f1], s1);
    atomicAdd(&lsum[128 + f0], ss0);
    atomicAdd(&lsum[128 + f1], ss1);
    if (lane == 0) atomicAdd(&lcnt, tot);
    __syncthreads();
    int rep = blockIdx.x & 63;
    atomicAdd(&partials[rep * 256 + tid], lsum[tid]);
    if (tid == 0) atomicAdd(&cntrep[rep], lcnt);
}

__global__ void k_finalize(const float* __restrict__ gamma, const float* __restrict__ beta,
                           const float* __restrict__ partials, const int* __restrict__ cntrep,
                           float* __restrict__ scsh) {
    int f = threadIdx.x;   // 128 threads
    float s = 0, ss = 0, cnt = 0;
    for (int r = 0; r < 64; ++r) {
        s  += partials[r * 256 + f];
        ss += partials[r * 256 + 128 + f];
        cnt += (float)cntrep[r];
    }
    float mean = s / cnt;
    float var = ss / cnt - mean * mean;
    float sc = gamma[f] / sqrtf(var + BN_EPS);
    scsh[f] = sc;
    scsh[128 + f] = beta[f] - mean * sc;
}

// --------------------------- self-loop pass --------------------------------
// msg=[x_i,0,0] -> MLP -> plain store (each output element written exactly once;
// doubles as initialization of d_out). wave handles 8 nodes.
// buf union: mk-stage [8][64] during GEMM1, then h [4][128] per 4-msg half.
__launch_bounds__(256, 2)
__global__ void k_self(const float* __restrict__ x, const float* __restrict__ W1,
                       const float* __restrict__ b1, const float* __restrict__ W2,
                       const float* __restrict__ b2, const float* __restrict__ scsh,
                       float* __restrict__ out) {
    __shared__ float w1s[64 * 128];
    __shared__ float w2s[128 * 64];
    __shared__ float buf[4][512];
    int tid = threadIdx.x;
    for (int i = tid; i < 64 * 128; i += 256) w1s[i] = W1[i];
    for (int i = tid; i < 128 * 64; i += 256) w2s[i] = W2[i];
    __syncthreads();
    int wave = tid >> 6, lane = tid & 63;
    int f0 = lane, f1 = lane + 64;
    float b10 = b1[f0], b11 = b1[f1];
    float sc0 = scsh[f0], sh0 = scsh[128 + f0];
    float sc1 = scsh[f1], sh1 = scsh[128 + f1];
    float bo = b2[lane];
    float* st = &buf[wave][0];

    int nbase = (blockIdx.x * 4 + wave) * 8;
#pragma unroll
    for (int mm = 0; mm < 8; ++mm)
        st[mm * 64 + lane] = x[(nbase + mm) * 64 + lane];
    __builtin_amdgcn_wave_barrier();

    float z0[8], z1[8];
#pragma unroll
    for (int mm = 0; mm < 8; ++mm) { z0[mm] = b10; z1[mm] = b11; }
    for (int k4 = 0; k4 < 16; ++k4) {
        float wa0 = w1s[(k4 * 4 + 0) * 128 + f0], wa1 = w1s[(k4 * 4 + 1) * 128 + f0];
        float wa2 = w1s[(k4 * 4 + 2) * 128 + f0], wa3 = w1s[(k4 * 4 + 3) * 128 + f0];
        float wb0 = w1s[(k4 * 4 + 0) * 128 + f1], wb1 = w1s[(k4 * 4 + 1) * 128 + f1];
        float wb2 = w1s[(k4 * 4 + 2) * 128 + f1], wb3 = w1s[(k4 * 4 + 3) * 128 + f1];
#pragma unroll
        for (int mm = 0; mm < 8; ++mm) {
            float4 mk = *(const float4*)&st[mm * 64 + k4 * 4];
            z0[mm] += mk.x * wa0 + mk.y * wa1 + mk.z * wa2 + mk.w * wa3;
            z1[mm] += mk.x * wb0 + mk.y * wb1 + mk.z * wb2 + mk.w * wb3;
        }
    }
    float h0[8], h1[8];
#pragma unroll
    for (int mm = 0; mm < 8; ++mm) {
        h0[mm] = fmaxf(z0[mm] * sc0 + sh0, 0.0f);
        h1[mm] = fmaxf(z1[mm] * sc1 + sh1, 0.0f);
    }
    // two 4-message halves through the unioned h buffer
#pragma unroll
    for (int half = 0; half < 2; ++half) {
        __builtin_amdgcn_wave_barrier();
#pragma unroll
        for (int mh = 0; mh < 4; ++mh) {
            st[mh * 128 + f0] = h0[half * 4 + mh];
            st[mh * 128 + f1] = h1[half * 4 + mh];
        }
        __builtin_amdgcn_wave_barrier();
        float o0 = bo, o1 = bo, o2 = bo, o3 = bo;
        for (int f4 = 0; f4 < 32; ++f4) {
            float u0 = w2s[(f4 * 4 + 0) * 64 + lane], u1 = w2s[(f4 * 4 + 1) * 64 + lane];
            float u2 = w2s[(f4 * 4 + 2) * 64 + lane], u3 = w2s[(f4 * 4 + 3) * 64 + lane];
            float4 hA = *(const float4*)&st[0 * 128 + f4 * 4];
            float4 hB = *(const float4*)&st[1 * 128 + f4 * 4];
            float4 hC = *(const float4*)&st[2 * 128 + f4 * 4];
            float4 hD = *(const float4*)&st[3 * 128 + f4 * 4];
            o0 += hA.x * u0 + hA.y * u1 + hA.z * u2 + hA.w * u3;
            o1 += hB.x * u0 + hB.y * u1 + hB.z * u2 + hB.w * u3;
            o2 += hC.x * u0 + hC.y * u1 + hC.z * u2 + hC.w * u3;
            o3 += hD.x * u0 + hD.y * u1 + hD.z * u2 + hD.w * u3;
        }
        float os[4] = {o0, o1, o2, o3};
#pragma unroll
        for (int mh = 0; mh < 4; ++mh) {
            int n = nbase + half * 4 + mh;
            out[(n >> 10) * 65536 + lane * 1024 + (n & 1023)] = os[mh];
        }
        __builtin_amdgcn_wave_barrier();
    }
}

// --------------------------- neighbor pass ---------------------------------
// wave-per-query; all K messages share target pix(q): max in registers, then
// one atomic per (query, feature). Runs after k_self initialized d_out.
__launch_bounds__(256, 2)
__global__ void k_nbr(const float* __restrict__ x, const float* __restrict__ pos,
                      const float* __restrict__ W1, const float* __restrict__ b1,
                      const float* __restrict__ W2, const float* __restrict__ b2,
                      const float* __restrict__ scsh, const int* __restrict__ nbrs,
                      const int* __restrict__ nbr_cnt, float* __restrict__ out) {
    __shared__ float w1s[64 * 128];
    __shared__ float w2s[128 * 64];
    __shared__ float buf[4][512];
    int tid = threadIdx.x;
    for (int i = tid; i < 64 * 128; i += 256) w1s[i] = W1[i];
    for (int i = tid; i < 128 * 64; i += 256) w2s[i] = W2[i];
    __syncthreads();
    int wave = tid >> 6, lane = tid & 63;
    int q = blockIdx.x * 4 + wave;
    int f0 = lane, f1 = lane + 64;
    int b = q >> 10;
    float qx = pos[2 * q], qy = pos[2 * q + 1];
    int row = min(max((int)(qy * 32.0f), 0), 31);
    int col = min(max((int)(qx * 32.0f), 0), 31);
    int pixq = (b << 10) + row * 32 + col;
    float tx = pos[2 * pixq], ty = pos[2 * pixq + 1];
    int m = nbr_cnt[q];
    float b10 = b1[f0], b11 = b1[f1];
    float w64f0 = W1[64 * 128 + f0], w65f0 = W1[65 * 128 + f0];
    float w64f1 = W1[64 * 128 + f1], w65f1 = W1[65 * 128 + f1];
    float sc0 = scsh[f0], sh0 = scsh[128 + f0];
    float sc1 = scsh[f1], sh1 = scsh[128 + f1];
    float bo = b2[lane];
    float omax = -__builtin_inff();
    float* st = &buf[wave][0];

    for (int basei = 0; basei < m; basei += 8) {
        int g = min(8, m - basei);
        float rx[8], ry[8];
#pragma unroll
        for (int mm = 0; mm < 8; ++mm) { rx[mm] = 0.0f; ry[mm] = 0.0f; }
        __builtin_amdgcn_wave_barrier();
#pragma unroll
        for (int mm = 0; mm < 8; ++mm) {
            if (mm < g) {
                int src = nbrs[q * KNB + basei + mm];
                rx[mm] = pos[2 * src] - tx;
                ry[mm] = pos[2 * src + 1] - ty;
                st[mm * 64 + lane] = x[src * 64 + lane];
            }
        }
        __builtin_amdgcn_wave_barrier();
        float z0[8], z1[8];
#pragma unroll
        for (int mm = 0; mm < 8; ++mm) { z0[mm] = b10; z1[mm] = b11; }
        for (int k4 = 0; k4 < 16; ++k4) {
            float wa0 = w1s[(k4 * 4 + 0) * 128 + f0], wa1 = w1s[(k4 * 4 + 1) * 128 + f0];
            float wa2 = w1s[(k4 * 4 + 2) * 128 + f0], wa3 = w1s[(k4 * 4 + 3) * 128 + f0];
            float wb0 = w1s[(k4 * 4 + 0) * 128 + f1], wb1 = w1s[(k4 * 4 + 1) * 128 + f1];
            float wb2 = w1s[(k4 * 4 + 2) * 128 + f1], wb3 = w1s[(k4 * 4 + 3) * 128 + f1];
#pragma unroll
            for (int mm = 0; mm < 8; ++mm) {
                float4 mk = *(const float4*)&st[mm * 64 + k4 * 4];
                z0[mm] += mk.x * wa0 + mk.y * wa1 + mk.z * wa2 + mk.w * wa3;
                z1[mm] += mk.x * wb0 + mk.y * wb1 + mk.z * wb2 + mk.w * wb3;
            }
        }
        float h0[8], h1[8];
#pragma unroll
        for (int mm = 0; mm < 8; ++mm) {
            float zz0 = z0[mm] + rx[mm] * w64f0 + ry[mm] * w65f0;
            float zz1 = z1[mm] + rx[mm] * w64f1 + ry[mm] * w65f1;
            h0[mm] = fmaxf(zz0 * sc0 + sh0, 0.0f);
            h1[mm] = fmaxf(zz1 * sc1 + sh1, 0.0f);
        }
        // two 4-message halves through the unioned h buffer
#pragma unroll
        for (int half = 0; half < 2; ++half) {
            int hbase = half * 4;
            if (hbase >= g) break;
            __builtin_amdgcn_wave_barrier();
#pragma unroll
            for (int mh = 0; mh < 4; ++mh) {
                if (hbase + mh < g) {
                    st[mh * 128 + f0] = h0[hbase + mh];
                    st[mh * 128 + f1] = h1[hbase + mh];
                }
            }
            __builtin_amdgcn_wave_barrier();
            float o0 = bo, o1 = bo, o2 = bo, o3 = bo;
            for (int f4 = 0; f4 < 32; ++f4) {
                float u0 = w2s[(f4 * 4 + 0) * 64 + lane], u1 = w2s[(f4 * 4 + 1) * 64 + lane];
                float u2 = w2s[(f4 * 4 + 2) * 64 + lane], u3 = w2s[(f4 * 4 + 3) * 64 + lane];
                float4 hA = *(const float4*)&st[0 * 128 + f4 * 4];
                float4 hB = *(const float4*)&st[1 * 128 + f4 * 4];
                float4 hC = *(const float4*)&st[2 * 128 + f4 * 4];
                float4 hD = *(const float4*)&st[3 * 128 + f4 * 4];
                o0 += hA.x * u0 + hA.y * u1 + hA.z * u2 + hA.w * u3;
                o1 += hB.x * u0 + hB.y * u1 + hB.z * u2 + hB.w * u3;
                o2 += hC.x * u0 + hC.y * u1 + hC.z * u2 + hC.w * u3;
                o3 += hD.x * u0 + hD.y * u1 + hD.z * u2 + hD.w * u3;
            }
            if (hbase + 0 < g) omax = fmaxf(omax, o0);
            if (hbase + 1 < g) omax = fmaxf(omax, o1);
            if (hbase + 2 < g) omax = fmaxf(omax, o2);
            if (hbase + 3 < g) omax = fmaxf(omax, o3);
            __builtin_amdgcn_wave_barrier();
        }
    }
    if (m > 0) {
        atomic_max_float(&out[(pixq >> 10) * 65536 + lane * 1024 + (pixq & 1023)], omax);
    }
}

extern "C" void kernel_launch(void* const* d_in, const int* in_sizes, int n_in,
                              void* d_out, int out_size, void* d_ws, size_t ws_size,
                              hipStream_t stream) {
    const float* x     = (const float*)d_in[0];
    const float* pos   = (const float*)d_in[1];
    // d_in[2] = batch (unused: points are sorted, b = idx >> 10)
    const float* W1    = (const float*)d_in[3];
    const float* b1    = (const float*)d_in[4];
    const float* gamma = (const float*)d_in[5];
    const float* beta  = (const float*)d_in[6];
    const float* W2    = (const float*)d_in[7];
    const float* b2    = (const float*)d_in[8];
    float* out = (float*)d_out;
    char* ws = (char*)d_ws;
    int*   nbrs     = (int*)(ws + WS_NBRS);
    int*   nbr_cnt  = (int*)(ws + WS_NBRCNT);
    float* partials = (float*)(ws + WS_PART);
    int*   cntrep   = (int*)(ws + WS_CNTREP);
    float* scsh     = (float*)(ws + WS_SCSH);

    k_init<<<64, 256, 0, stream>>>(partials, cntrep);
    k_ballquery<<<NPTS, 64, 0, stream>>>(pos, nbrs, nbr_cnt);
    k_stats<<<NPTS / 4, 256, 0, stream>>>(x, pos, W1, b1, nbrs, nbr_cnt, partials, cntrep);
    k_finalize<<<1, 128, 0, stream>>>(gamma, beta, partials, cntrep, scsh);
    k_self<<<NPTS / 32, 256, 0, stream>>>(x, W1, b1, W2, b2, scsh, out);
    k_nbr<<<NPTS / 4, 256, 0, stream>>>(x, pos, W1, b1, W2, b2, scsh, nbrs, nbr_cnt, out);
}

// Round 3
// 395.831 us; speedup vs baseline: 47.4074x; 3.6294x over previous
//
#include <hip/hip_runtime.h>
#include <math.h>

// ---------------------------------------------------------------------------
// PointsToImage: ball-query (K=32, R=0.1) -> PointNetConv msg=[x_j, pos_j-pos_dst]
// -> Linear(66,128) -> masked-BatchNorm -> ReLU -> Linear(128,64) -> scatter-max
// into pixel nodes, output [B=32, F=64, 32, 32] fp32.
//
// R3 restructure:
//  (a) GEMM1 decomposition: y = x @ W1[:64] + b1 computed once per NODE (k_y);
//      per-edge z = y[src] + rx*W1[64] + ry*W1[65]  (4 FMA/lane instead of 128).
//  (b) GEMM2 on MFMA bf16: h (bf16) staged in LDS in A-frag layout
//      (A[m=lane&15][k=quad*8+j], row stride 272 B for bank balance), W2
//      pre-packed into B-frag layout (k_prep) and held in 64 VGPRs per wave.
//      C layout: col=lane&15, row=quad*4+reg -> max over edges = 3 fmax +
//      shfl_xor(16,32); final feature index = lane.
// Pipeline: k_prep -> k_ballquery -> k_y -> k_stats -> k_finalize -> k_self -> k_out
// ---------------------------------------------------------------------------

#define NPTS   32768
#define PB     1024
#define KNB    32
#define BN_EPS 1e-5f

// workspace layout (bytes)
#define WS_NBRS     0u           // int[NPTS*KNB]      = 4194304
#define WS_NBRCNT   4194304u     // int[NPTS]          = 131072
#define WS_PART     4325376u     // float[64*256]      = 65536
#define WS_CNTREP   4390912u     // int[64]            = 256
#define WS_SCSH     4391168u     // float[256]         = 1024
#define WS_W2B      4392192u     // ushort[8192]       = 16384  (W2 in B-frag layout, bf16)
#define WS_Y        4408576u     // float[NPTS*128]    = 16 MB  (paired: [node][lane*2+{0,1}] = f=lane, f=lane+64)

typedef __attribute__((ext_vector_type(8))) short short8;
typedef __attribute__((ext_vector_type(4))) float floatx4;

__device__ __forceinline__ unsigned short f2bf(float f) {
    unsigned int u = __float_as_uint(f);
    unsigned int r = u + 0x7fffu + ((u >> 16) & 1u);   // RNE
    return (unsigned short)(r >> 16);
}

__device__ __forceinline__ void atomic_max_float(float* addr, float v) {
    if (v >= 0.0f) atomicMax((int*)addr, __float_as_int(v));
    else           atomicMin((unsigned int*)addr, __float_as_uint(v));
}

// ------------------- prep: zero partials, pack W2 into B-frag bf16 ----------
// B-frag for mfma_f32_16x16x32_bf16: lane L holds B[k=(L>>4)*8+j][n=L&15].
// w2b[((t*4+ks)*64+L)*8 + j] = bf16(W2[(ks*32+(L>>4)*8+j)*64 + t*16+(L&15)])
__global__ void k_prep(const float* __restrict__ W2, unsigned short* __restrict__ w2b,
                       float* __restrict__ partials, int* __restrict__ cntrep) {
    int t = blockIdx.x * 256 + threadIdx.x;     // 64 blocks * 256 = 16384
    partials[t] = 0.0f;
    if (t < 64) cntrep[t] = 0;
    if (t < 8192) {
        int j  = t & 7;
        int L  = (t >> 3) & 63;
        int ks = (t >> 9) & 3;
        int t4 = t >> 11;
        int k = ks * 32 + (L >> 4) * 8 + j;
        int n = t4 * 16 + (L & 15);
        w2b[t] = f2bf(W2[k * 64 + n]);
    }
}

// --------------------------- ball query (unchanged, exact) ------------------
__global__ void k_ballquery(const float* __restrict__ pos,
                            int* __restrict__ nbrs, int* __restrict__ nbr_cnt) {
    int q = blockIdx.x;
    int lane = threadIdx.x;
    int base = (q >> 10) << 10;
    float qx = pos[2 * q], qy = pos[2 * q + 1];
    int row = min(max((int)(qy * 32.0f), 0), 31);
    int col = min(max((int)(qx * 32.0f), 0), 31);
    int pixq = base + row * 32 + col;

    __shared__ float cd2[256];
    __shared__ int   cidx[256];
    __shared__ int   cnt, ocnt;
    if (lane == 0) { cnt = 0; ocnt = 0; }
    __syncthreads();

    for (int j = lane; j < PB; j += 64) {
        int g = base + j;
        float dx = pos[2 * g]     - qx;
        float dy = pos[2 * g + 1] - qy;
        float d2 = __fadd_rn(__fmul_rn(dx, dx), __fmul_rn(dy, dy)); // no FMA contraction
        if (d2 <= 0.01f) {
            int s = atomicAdd(&cnt, 1);
            if (s < 256) { cd2[s] = d2; cidx[s] = g; }
        }
    }
    __syncthreads();
    int c = min(cnt, 256);
    for (int i = lane; i < c; i += 64) {
        float d2i = cd2[i]; int gi = cidx[i];
        int rank = 0;
        for (int t = 0; t < c; ++t) {
            float d2t = cd2[t]; int gt = cidx[t];
            rank += (d2t < d2i || (d2t == d2i && gt < gi)) ? 1 : 0;
        }
        if (rank < KNB && gi != pixq) {          // top-K, then remove_self_loops
            int s = atomicAdd(&ocnt, 1);
            nbrs[q * KNB + s] = gi;
        }
    }
    __syncthreads();
    if (lane == 0) nbr_cnt[q] = ocnt;
}

// --------------------------- node-level GEMM1: y = x@W1[:64] + b1 -----------
// wave handles 8 nodes; writes paired float2 (f=lane, f=lane+64).
__launch_bounds__(256, 2)
__global__ void k_y(const float* __restrict__ x, const float* __restrict__ W1,
                    const float* __restrict__ b1, float* __restrict__ yws) {
    __shared__ float w1s[64 * 128];
    __shared__ float stage[4][512];
    int tid = threadIdx.x;
    for (int i = tid; i < 64 * 128; i += 256) w1s[i] = W1[i];
    __syncthreads();
    int wave = tid >> 6, lane = tid & 63;
    float b10 = b1[lane], b11 = b1[64 + lane];
    float* st = &stage[wave][0];
    int nbase = (blockIdx.x * 4 + wave) * 8;
#pragma unroll
    for (int mm = 0; mm < 8; ++mm)
        st[mm * 64 + lane] = x[(nbase + mm) * 64 + lane];
    __builtin_amdgcn_wave_barrier();
    float z0[8], z1[8];
#pragma unroll
    for (int mm = 0; mm < 8; ++mm) { z0[mm] = b10; z1[mm] = b11; }
    for (int k4 = 0; k4 < 16; ++k4) {
        float wa0 = w1s[(k4 * 4 + 0) * 128 + lane], wa1 = w1s[(k4 * 4 + 1) * 128 + lane];
        float wa2 = w1s[(k4 * 4 + 2) * 128 + lane], wa3 = w1s[(k4 * 4 + 3) * 128 + lane];
        float wb0 = w1s[(k4 * 4 + 0) * 128 + 64 + lane], wb1 = w1s[(k4 * 4 + 1) * 128 + 64 + lane];
        float wb2 = w1s[(k4 * 4 + 2) * 128 + 64 + lane], wb3 = w1s[(k4 * 4 + 3) * 128 + 64 + lane];
#pragma unroll
        for (int mm = 0; mm < 8; ++mm) {
            float4 mk = *(const float4*)&st[mm * 64 + k4 * 4];
            z0[mm] += mk.x * wa0 + mk.y * wa1 + mk.z * wa2 + mk.w * wa3;
            z1[mm] += mk.x * wb0 + mk.y * wb1 + mk.z * wb2 + mk.w * wb3;
        }
    }
#pragma unroll
    for (int mm = 0; mm < 8; ++mm) {
        float2 o; o.x = z0[mm]; o.y = z1[mm];
        *(float2*)&yws[(nbase + mm) * 128 + lane * 2] = o;
    }
}

// --------------------------- stats pass (y-gather, cheap) -------------------
__launch_bounds__(256)
__global__ void k_stats(const float* __restrict__ y, const float* __restrict__ pos,
                        const float* __restrict__ W1,
                        const int* __restrict__ nbrs, const int* __restrict__ nbr_cnt,
                        float* __restrict__ partials, int* __restrict__ cntrep) {
    __shared__ float lsum[256];
    __shared__ int lcnt;
    int tid = threadIdx.x;
    lsum[tid] = 0.0f;
    if (tid == 0) lcnt = 0;
    __syncthreads();
    int wave = tid >> 6, lane = tid & 63;
    int q = blockIdx.x * 4 + wave;
    int m = nbr_cnt[q];
    int b = q >> 10;
    float qx = pos[2 * q], qy = pos[2 * q + 1];
    int row = min(max((int)(qy * 32.0f), 0), 31);
    int col = min(max((int)(qx * 32.0f), 0), 31);
    int pixq = (b << 10) + row * 32 + col;
    float tx = pos[2 * pixq], ty = pos[2 * pixq + 1];
    float w64f0 = W1[8192 + lane], w65f0 = W1[8320 + lane];
    float w64f1 = W1[8256 + lane], w65f1 = W1[8384 + lane];
    int nv = (lane < m) ? nbrs[q * KNB + lane] : q;
    float px = pos[2 * nv], py = pos[2 * nv + 1];
    // self message: z = y[q], relpos = 0
    float2 ys = *(const float2*)&y[q * 128 + lane * 2];
    float s0 = ys.x, ss0 = ys.x * ys.x;
    float s1 = ys.y, ss1 = ys.y * ys.y;
    for (int base = 0; base < m; base += 8) {
        float2 yv[8]; float rxx[8], ryy[8];
#pragma unroll
        for (int j = 0; j < 8; ++j) {
            int e = base + j;
            if (e < m) {
                int src = __shfl(nv, e);
                rxx[j] = __shfl(px, e) - tx;
                ryy[j] = __shfl(py, e) - ty;
                yv[j] = *(const float2*)&y[src * 128 + lane * 2];
            }
        }
#pragma unroll
        for (int j = 0; j < 8; ++j) {
            if (base + j < m) {
                float z0 = yv[j].x + rxx[j] * w64f0 + ryy[j] * w65f0;
                float z1 = yv[j].y + rxx[j] * w64f1 + ryy[j] * w65f1;
                s0 += z0; ss0 = fmaf(z0, z0, ss0);
                s1 += z1; ss1 = fmaf(z1, z1, ss1);
            }
        }
    }
    atomicAdd(&lsum[lane], s0);
    atomicAdd(&lsum[64 + lane], s1);
    atomicAdd(&lsum[128 + lane], ss0);
    atomicAdd(&lsum[192 + lane], ss1);
    if (lane == 0) atomicAdd(&lcnt, m + 1);
    __syncthreads();
    int rep = blockIdx.x & 63;
    atomicAdd(&partials[rep * 256 + tid], lsum[tid]);
    if (tid == 0) atomicAdd(&cntrep[rep], lcnt);
}

__global__ void k_finalize(const float* __restrict__ gamma, const float* __restrict__ beta,
                           const float* __restrict__ partials, const int* __restrict__ cntrep,
                           float* __restrict__ scsh) {
    int f = threadIdx.x;   // 128 threads
    float s = 0, ss = 0, cnt = 0;
    for (int r = 0; r < 64; ++r) {
        s  += partials[r * 256 + f];
        ss += partials[r * 256 + 128 + f];
        cnt += (float)cntrep[r];
    }
    float mean = s / cnt;
    float var = ss / cnt - mean * mean;
    float sc = gamma[f] / sqrtf(var + BN_EPS);
    scsh[f] = sc;
    scsh[128 + f] = beta[f] - mean * sc;
}

// --------------------------- self pass (MFMA, plain store = out init) -------
__launch_bounds__(256)
__global__ void k_self(const float* __restrict__ y, const float* __restrict__ scsh,
                       const unsigned short* __restrict__ w2b, const float* __restrict__ b2,
                       float* __restrict__ out) {
    __shared__ unsigned short hbuf[4][16 * 136];   // 272 B row stride (bank balance)
    int tid = threadIdx.x, wave = tid >> 6, lane = tid & 63;
    unsigned short* hb = hbuf[wave];
    short8 bfrag[4][4];
#pragma unroll
    for (int t = 0; t < 4; ++t)
#pragma unroll
        for (int ks = 0; ks < 4; ++ks)
            bfrag[t][ks] = *(const short8*)&w2b[((t * 4 + ks) * 64 + lane) * 8];
    float sc0 = scsh[lane],      sh0 = scsh[128 + lane];
    float sc1 = scsh[64 + lane], sh1 = scsh[192 + lane];
    float b2v0 = b2[(lane & 15)], b2v1 = b2[16 + (lane & 15)];
    float b2v2 = b2[32 + (lane & 15)], b2v3 = b2[48 + (lane & 15)];

    int nbase = (blockIdx.x * 4 + wave) * 16;
#pragma unroll
    for (int c = 0; c < 2; ++c) {
        float2 yv[8];
#pragma unroll
        for (int j = 0; j < 8; ++j)
            yv[j] = *(const float2*)&y[(nbase + c * 8 + j) * 128 + lane * 2];
#pragma unroll
        for (int j = 0; j < 8; ++j) {
            int e = c * 8 + j;
            hb[e * 136 + lane]      = f2bf(fmaxf(yv[j].x * sc0 + sh0, 0.0f));
            hb[e * 136 + 64 + lane] = f2bf(fmaxf(yv[j].y * sc1 + sh1, 0.0f));
        }
    }
    __builtin_amdgcn_wave_barrier();
    floatx4 acc0 = {0,0,0,0}, acc1 = {0,0,0,0}, acc2 = {0,0,0,0}, acc3 = {0,0,0,0};
#pragma unroll
    for (int ks = 0; ks < 4; ++ks) {
        short8 a = *(const short8*)&hb[(lane & 15) * 136 + ks * 32 + (lane >> 4) * 8];
        acc0 = __builtin_amdgcn_mfma_f32_16x16x32_bf16(a, bfrag[0][ks], acc0, 0, 0, 0);
        acc1 = __builtin_amdgcn_mfma_f32_16x16x32_bf16(a, bfrag[1][ks], acc1, 0, 0, 0);
        acc2 = __builtin_amdgcn_mfma_f32_16x16x32_bf16(a, bfrag[2][ks], acc2, 0, 0, 0);
        acc3 = __builtin_amdgcn_mfma_f32_16x16x32_bf16(a, bfrag[3][ks], acc3, 0, 0, 0);
    }
    int nrow = nbase + (lane >> 4) * 4;
#pragma unroll
    for (int r = 0; r < 4; ++r) {
        int n = nrow + r;
        int obase = (n >> 10) * 65536 + (n & 1023);
        out[obase + ((lane & 15)) * 1024]        = acc0[r] + b2v0;
        out[obase + (16 + (lane & 15)) * 1024]   = acc1[r] + b2v1;
        out[obase + (32 + (lane & 15)) * 1024]   = acc2[r] + b2v2;
        out[obase + (48 + (lane & 15)) * 1024]   = acc3[r] + b2v3;
    }
}

// --------------------------- neighbor pass (MFMA + atomic max) --------------
// persistent wave handles 8 queries; W2 B-frags live in 64 VGPRs.
__launch_bounds__(256)
__global__ void k_out(const float* __restrict__ y, const float* __restrict__ pos,
                      const float* __restrict__ W1, const float* __restrict__ scsh,
                      const unsigned short* __restrict__ w2b, const float* __restrict__ b2,
                      const int* __restrict__ nbrs, const int* __restrict__ nbr_cnt,
                      float* __restrict__ out) {
    __shared__ unsigned short hbuf[4][16 * 136];
    int tid = threadIdx.x, wave = tid >> 6, lane = tid & 63;
    unsigned short* hb = hbuf[wave];
    short8 bfrag[4][4];
#pragma unroll
    for (int t = 0; t < 4; ++t)
#pragma unroll
        for (int ks = 0; ks < 4; ++ks)
            bfrag[t][ks] = *(const short8*)&w2b[((t * 4 + ks) * 64 + lane) * 8];
    float sc0 = scsh[lane],      sh0 = scsh[128 + lane];
    float sc1 = scsh[64 + lane], sh1 = scsh[192 + lane];
    float w64f0 = W1[8192 + lane], w65f0 = W1[8320 + lane];
    float w64f1 = W1[8256 + lane], w65f1 = W1[8384 + lane];
    float b2l = b2[lane];
    int wid = blockIdx.x * 4 + wave;     // 4096 waves

    for (int qi = 0; qi < 8; ++qi) {
        int q = wid * 8 + qi;
        int m = nbr_cnt[q];
        if (m == 0) continue;
        int b = q >> 10;
        float qx = pos[2 * q], qy = pos[2 * q + 1];
        int row = min(max((int)(qy * 32.0f), 0), 31);
        int col = min(max((int)(qx * 32.0f), 0), 31);
        int pixq = (b << 10) + row * 32 + col;
        float tx = pos[2 * pixq], ty = pos[2 * pixq + 1];
        int nv = (lane < m) ? nbrs[q * KNB + lane] : q;
        float px = pos[2 * nv], py = pos[2 * nv + 1];
        floatx4 om0 = {-INFINITY,-INFINITY,-INFINITY,-INFINITY};
        floatx4 om1 = om0, om2 = om0, om3 = om0;
        int ntile = (m + 15) >> 4;
        for (int mt = 0; mt < ntile; ++mt) {
#pragma unroll
            for (int c = 0; c < 2; ++c) {
                float2 yv[8]; float rxx[8], ryy[8];
#pragma unroll
                for (int j = 0; j < 8; ++j) {
                    int e = mt * 16 + c * 8 + j;
                    if (e < m) {
                        int src = __shfl(nv, e);
                        rxx[j] = __shfl(px, e) - tx;
                        ryy[j] = __shfl(py, e) - ty;
                        yv[j] = *(const float2*)&y[src * 128 + lane * 2];
                    } else {
                        rxx[j] = 0.0f; ryy[j] = 0.0f;
                        yv[j].x = 0.0f; yv[j].y = 0.0f;
                    }
                }
#pragma unroll
                for (int j = 0; j < 8; ++j) {
                    int e16 = c * 8 + j;
                    float z0 = yv[j].x + rxx[j] * w64f0 + ryy[j] * w65f0;
                    float z1 = yv[j].y + rxx[j] * w64f1 + ryy[j] * w65f1;
                    hb[e16 * 136 + lane]      = f2bf(fmaxf(z0 * sc0 + sh0, 0.0f));
                    hb[e16 * 136 + 64 + lane] = f2bf(fmaxf(z1 * sc1 + sh1, 0.0f));
                }
            }
            __builtin_amdgcn_wave_barrier();
            floatx4 acc0 = {0,0,0,0}, acc1 = {0,0,0,0}, acc2 = {0,0,0,0}, acc3 = {0,0,0,0};
#pragma unroll
            for (int ks = 0; ks < 4; ++ks) {
                short8 a = *(const short8*)&hb[(lane & 15) * 136 + ks * 32 + (lane >> 4) * 8];
                acc0 = __builtin_amdgcn_mfma_f32_16x16x32_bf16(a, bfrag[0][ks], acc0, 0, 0, 0);
                acc1 = __builtin_amdgcn_mfma_f32_16x16x32_bf16(a, bfrag[1][ks], acc1, 0, 0, 0);
                acc2 = __builtin_amdgcn_mfma_f32_16x16x32_bf16(a, bfrag[2][ks], acc2, 0, 0, 0);
                acc3 = __builtin_amdgcn_mfma_f32_16x16x32_bf16(a, bfrag[3][ks], acc3, 0, 0, 0);
            }
            __builtin_amdgcn_wave_barrier();
#pragma unroll
            for (int r = 0; r < 4; ++r) {
                int e = mt * 16 + (lane >> 4) * 4 + r;
                if (e < m) {
                    om0[r] = fmaxf(om0[r], acc0[r]);
                    om1[r] = fmaxf(om1[r], acc1[r]);
                    om2[r] = fmaxf(om2[r], acc2[r]);
                    om3[r] = fmaxf(om3[r], acc3[r]);
                }
            }
        }
        float v0 = fmaxf(fmaxf(om0[0], om0[1]), fmaxf(om0[2], om0[3]));
        float v1 = fmaxf(fmaxf(om1[0], om1[1]), fmaxf(om1[2], om1[3]));
        float v2 = fmaxf(fmaxf(om2[0], om2[1]), fmaxf(om2[2], om2[3]));
        float v3 = fmaxf(fmaxf(om3[0], om3[1]), fmaxf(om3[2], om3[3]));
        v0 = fmaxf(v0, __shfl_xor(v0, 16)); v0 = fmaxf(v0, __shfl_xor(v0, 32));
        v1 = fmaxf(v1, __shfl_xor(v1, 16)); v1 = fmaxf(v1, __shfl_xor(v1, 32));
        v2 = fmaxf(v2, __shfl_xor(v2, 16)); v2 = fmaxf(v2, __shfl_xor(v2, 32));
        v3 = fmaxf(v3, __shfl_xor(v3, 16)); v3 = fmaxf(v3, __shfl_xor(v3, 32));
        int g = lane >> 4;   // feature = g*16 + (lane&15) = lane
        float vf = (g == 0) ? v0 : (g == 1) ? v1 : (g == 2) ? v2 : v3;
        vf += b2l;
        atomic_max_float(&out[b * 65536 + lane * 1024 + (pixq & 1023)], vf);
    }
}

extern "C" void kernel_launch(void* const* d_in, const int* in_sizes, int n_in,
                              void* d_out, int out_size, void* d_ws, size_t ws_size,
                              hipStream_t stream) {
    const float* x     = (const float*)d_in[0];
    const float* pos   = (const float*)d_in[1];
    // d_in[2] = batch (unused: points are sorted, b = idx >> 10)
    const float* W1    = (const float*)d_in[3];
    const float* b1    = (const float*)d_in[4];
    const float* gamma = (const float*)d_in[5];
    const float* beta  = (const float*)d_in[6];
    const float* W2    = (const float*)d_in[7];
    const float* b2    = (const float*)d_in[8];
    float* out = (float*)d_out;
    char* ws = (char*)d_ws;
    int*   nbrs     = (int*)(ws + WS_NBRS);
    int*   nbr_cnt  = (int*)(ws + WS_NBRCNT);
    float* partials = (float*)(ws + WS_PART);
    int*   cntrep   = (int*)(ws + WS_CNTREP);
    float* scsh     = (float*)(ws + WS_SCSH);
    unsigned short* w2b = (unsigned short*)(ws + WS_W2B);
    float* yws      = (float*)(ws + WS_Y);

    k_prep<<<64, 256, 0, stream>>>(W2, w2b, partials, cntrep);
    k_ballquery<<<NPTS, 64, 0, stream>>>(pos, nbrs, nbr_cnt);
    k_y<<<NPTS / 32, 256, 0, stream>>>(x, W1, b1, yws);
    k_stats<<<NPTS / 4, 256, 0, stream>>>(yws, pos, W1, nbrs, nbr_cnt, partials, cntrep);
    k_finalize<<<1, 128, 0, stream>>>(gamma, beta, partials, cntrep, scsh);
    k_self<<<NPTS / 64, 256, 0, stream>>>(yws, scsh, w2b, b2, out);
    k_out<<<NPTS / 32, 256, 0, stream>>>(yws, pos, W1, scsh, w2b, b2, nbrs, nbr_cnt, out);
}